// Round 11
// baseline (180.291 us; speedup 1.0000x reference)
//
#include <hip/hip_runtime.h>

#define N_NODES 100000
#define DIM 8
#define NB 128                 // nodes per bucket
#define BSHIFT 7               // log2(NB)
#define NBUCKETS ((N_NODES + NB - 1) / NB)   // 782
#define LSROW (NBUCKETS + 1)   // 783 (local-scan row incl. sentinel)
#define G1 2048                // partition blocks
#define ESPAN_MAX 3328         // LDS stage cap for scatter
#define CAP 9400               // max edges per bucket (mean 8184, ~13 sigma)

// ---------------- fallback (atomic path) ----------------
__global__ void init_neg_kernel(const float* __restrict__ x,
                                float* __restrict__ out, int n4) {
    int i = blockIdx.x * blockDim.x + threadIdx.x;
    if (i < n4) {
        float4 v = reinterpret_cast<const float4*>(x)[i];
        float4 o; o.x = -v.x; o.y = -v.y; o.z = -v.z; o.w = -v.w;
        reinterpret_cast<float4*>(out)[i] = o;
    }
}

__global__ void edge_scatter_atomic(const float* __restrict__ x,
                                    const int* __restrict__ row,
                                    const int* __restrict__ col,
                                    const float* __restrict__ w,
                                    float* __restrict__ out, int nE) {
    int e = blockIdx.x * blockDim.x + threadIdx.x;
    if (e >= nE) return;
    int r = row[e], c = col[e];
    float we = w[e];
    const float4* xr = reinterpret_cast<const float4*>(x + (size_t)r * DIM);
    const float4* xc = reinterpret_cast<const float4*>(x + (size_t)c * DIM);
    float4 a0 = xr[0], a1 = xr[1], b0 = xc[0], b1 = xc[1];
    float* o = out + (size_t)c * DIM;
    atomicAdd(o + 0, (a0.x - b0.x) * we); atomicAdd(o + 1, (a0.y - b0.y) * we);
    atomicAdd(o + 2, (a0.z - b0.z) * we); atomicAdd(o + 3, (a0.w - b0.w) * we);
    atomicAdd(o + 4, (a1.x - b1.x) * we); atomicAdd(o + 5, (a1.y - b1.y) * we);
    atomicAdd(o + 6, (a1.z - b1.z) * we); atomicAdd(o + 7, (a1.w - b1.w) * we);
}

// ---------------- R11 pipeline ----------------

// K1: per-block histogram + LOCAL exclusive scan, coalesced L[blk][0..782]
__global__ __launch_bounds__(256) void hist_scan_kernel(const int* __restrict__ col,
                                                        int nE, int espan,
                                                        unsigned* __restrict__ L) {
    __shared__ unsigned cnt[NBUCKETS];
    __shared__ unsigned part[256];
    int t = threadIdx.x, blk = blockIdx.x;
    long e0 = (long)blk * espan;
    long rem = (long)nE - e0;
    int n = (int)(rem > (long)espan ? espan : (rem < 0 ? 0 : rem));

    for (int i = t; i < NBUCKETS; i += 256) cnt[i] = 0;
    __syncthreads();
    for (int k = t; k < n; k += 256)
        atomicAdd(&cnt[((unsigned)col[e0 + k]) >> BSHIFT], 1u);
    __syncthreads();

    unsigned v[4], s = 0;
    #pragma unroll
    for (int j = 0; j < 4; ++j) {
        int b = 4 * t + j;
        v[j] = (b < NBUCKETS) ? cnt[b] : 0u;
        s += v[j];
    }
    part[t] = s; __syncthreads();
    for (int off = 1; off < 256; off <<= 1) {
        unsigned u = (t >= off) ? part[t - off] : 0u;
        __syncthreads();
        part[t] += u; __syncthreads();
    }
    unsigned base = part[t] - s;
    size_t lrow = (size_t)blk * LSROW;
    #pragma unroll
    for (int j = 0; j < 4; ++j) {
        int b = 4 * t + j;
        if (b < NBUCKETS) { L[lrow + b] = base; base += v[j]; }
    }
    if (t == 255) L[lrow + NBUCKETS] = part[255];   // == n (sentinel, used by col_scan)
}

// K2: tile transpose  in[R][C] -> out[C][R]
__global__ void transpose_kernel(const unsigned* __restrict__ in,
                                 unsigned* __restrict__ outp, int R, int C) {
    __shared__ unsigned tile[32][33];
    int tx = threadIdx.x, ty = threadIdx.y;
    int c0 = blockIdx.x * 32, r0 = blockIdx.y * 32;
    #pragma unroll
    for (int j = 0; j < 32; j += 8) {
        int r = r0 + ty + j, c = c0 + tx;
        if (r < R && c < C) tile[ty + j][tx] = in[(size_t)r * C + c];
    }
    __syncthreads();
    #pragma unroll
    for (int j = 0; j < 32; j += 8) {
        int c = c0 + ty + j, r = r0 + tx;
        if (r < R && c < C) outp[(size_t)c * R + r] = tile[tx][ty + j];
    }
}

// K3: per-bucket cross-block scan (coalesced rows of LT) -> OT, bucketTotal
__global__ __launch_bounds__(1024) void col_scan_kernel(const unsigned* __restrict__ LT,
                                                        unsigned* __restrict__ OT,
                                                        unsigned* __restrict__ bucketTotal) {
    __shared__ unsigned part[1024];
    int b = blockIdx.x, t = threadIdx.x;
    const unsigned* r0 = LT + (size_t)b * G1;
    const unsigned* r1 = LT + (size_t)(b + 1) * G1;
    unsigned c0 = r1[2 * t] - r0[2 * t];
    unsigned c1 = r1[2 * t + 1] - r0[2 * t + 1];
    part[t] = c0 + c1; __syncthreads();
    for (int off = 1; off < 1024; off <<= 1) {
        unsigned u = (t >= off) ? part[t - off] : 0u;
        __syncthreads();
        part[t] += u; __syncthreads();
    }
    unsigned ex = part[t] - (c0 + c1);
    OT[(size_t)b * G1 + 2 * t]     = ex;
    OT[(size_t)b * G1 + 2 * t + 1] = ex + c0;
    if (t == 1023) bucketTotal[b] = part[1023];
}

// K4: exclusive scan over bucket totals
__global__ __launch_bounds__(1024) void bucket_scan_kernel(const unsigned* __restrict__ bucketTotal,
                                                           unsigned* __restrict__ bucketStart) {
    __shared__ unsigned sc[1024];
    int t = threadIdx.x;
    unsigned v = (t < NBUCKETS) ? bucketTotal[t] : 0u;
    sc[t] = v; __syncthreads();
    for (int off = 1; off < 1024; off <<= 1) {
        unsigned u = (t >= off) ? sc[t - off] : 0u;
        __syncthreads();
        sc[t] += u; __syncthreads();
    }
    if (t < NBUCKETS) bucketStart[t] = sc[t] - v;
    if (t == NBUCKETS - 1) bucketStart[NBUCKETS] = sc[t];
}

// K5: blockOffs[blk][b] = OT[b][blk] + bucketStart[b]  (tile transpose)
__global__ void add_transpose_kernel(const unsigned* __restrict__ OT,
                                     const unsigned* __restrict__ bucketStart,
                                     unsigned* __restrict__ blockOffs) {
    __shared__ unsigned tile[32][33];
    int tx = threadIdx.x, ty = threadIdx.y;
    int blk0 = blockIdx.x * 32, b0 = blockIdx.y * 32;
    #pragma unroll
    for (int j = 0; j < 32; j += 8) {
        int b = b0 + ty + j, blk = blk0 + tx;
        if (b < NBUCKETS && blk < G1)
            tile[ty + j][tx] = OT[(size_t)b * G1 + blk] + bucketStart[b];
    }
    __syncthreads();
    #pragma unroll
    for (int j = 0; j < 32; j += 8) {
        int blk = blk0 + ty + j, b = b0 + tx;
        if (b < NBUCKETS && blk < G1)
            blockOffs[(size_t)blk * NBUCKETS + b] = tile[tx][ty + j];
    }
}

// K6: single-pass local sort + coalesced run-flush. LDS trimmed to 39.5 KB
// (lst+gbase merged into diff) -> 4 blocks/CU = 32 waves.
__global__ __launch_bounds__(512) void scatter2_kernel(
        const int* __restrict__ row,
        const int* __restrict__ col,
        const float* __restrict__ w,
        int nE, int espan,
        const unsigned* __restrict__ L,
        const unsigned* __restrict__ blockOffs,
        uint2* __restrict__ payloadA) {
    __shared__ uint2 stage[ESPAN_MAX];           // 26.6 KB
    __shared__ unsigned short sbkt[ESPAN_MAX];   // 6.7 KB
    __shared__ unsigned cur[NBUCKETS];           // 3.1 KB (sort cursors)
    __shared__ unsigned diff[NBUCKETS];          // 3.1 KB (gbase - lst)
    int t = threadIdx.x, blk = blockIdx.x;
    long e0 = (long)blk * espan;
    long rem = (long)nE - e0;
    int n = (int)(rem > (long)espan ? espan : (rem < 0 ? 0 : rem));
    size_t lrow = (size_t)blk * LSROW;

    for (int i = t; i < NBUCKETS; i += 512) {
        unsigned lv = L[lrow + i];
        cur[i]  = lv;                                        // cursor = local start
        diff[i] = blockOffs[(size_t)blk * NBUCKETS + i] - lv; // gpos = diff + k
    }
    __syncthreads();

    for (int k = t; k < n; k += 512) {
        unsigned c = (unsigned)col[e0 + k];
        unsigned b = c >> BSHIFT;
        unsigned pos = atomicAdd(&cur[b], 1u);
        stage[pos] = make_uint2(((unsigned)row[e0 + k] << BSHIFT) | (c & (NB - 1)),
                                __float_as_uint(w[e0 + k]));
        sbkt[pos] = (unsigned short)b;
    }
    __syncthreads();

    for (int k = t; k < n; k += 512) {
        unsigned b = sbkt[k];
        payloadA[diff[b] + (unsigned)k] = stage[k];
    }
}

// K7 (fused, u16-index stage): per-bucket node sort of INDICES + register
// gather reading payloadA via L2. LDS ~21 KB -> 4 blocks/CU = 32 waves.
__global__ __launch_bounds__(512) void bucket_sort_gather_kernel(
        const float* __restrict__ x,
        const uint2* __restrict__ payloadA,
        const unsigned* __restrict__ bucketStart,
        float* __restrict__ out) {
    __shared__ unsigned short sidx[CAP];  // 18.8 KB
    __shared__ unsigned cnt[NB];
    __shared__ unsigned scanb[NB];
    __shared__ unsigned exs[NB + 1];
    int b = blockIdx.x, t = threadIdx.x;
    int e0 = (int)bucketStart[b], e1 = (int)bucketStart[b + 1];
    int n = e1 - e0;

    if (t < NB) cnt[t] = 0;
    __syncthreads();

    if (n <= CAP) {
        for (int k = t; k < n; k += 512)
            atomicAdd(&cnt[payloadA[e0 + k].x & (NB - 1)], 1u);
        __syncthreads();
        if (t < NB) scanb[t] = cnt[t];
        __syncthreads();
        for (int off = 1; off < NB; off <<= 1) {
            unsigned v = 0;
            if (t < NB && t >= off) v = scanb[t - off];
            __syncthreads();
            if (t < NB) scanb[t] += v;
            __syncthreads();
        }
        if (t < NB) {
            unsigned ex = scanb[t] - cnt[t];
            exs[t] = ex;
            cnt[t] = ex;                  // cursor
        }
        if (t == 0) exs[NB] = (unsigned)n;
        __syncthreads();

        for (int k = t; k < n; k += 512) {
            unsigned node = payloadA[e0 + k].x & (NB - 1);
            unsigned pos = atomicAdd(&cnt[node], 1u);
            sidx[pos] = (unsigned short)k;
        }
        __syncthreads();

        for (int slot = t; slot < NB * DIM; slot += 512) {
            int node = slot >> 3, d = slot & 7;
            int gn = b * NB + node;
            if (gn >= N_NODES) continue;
            float xc = x[(size_t)gn * DIM + d];
            int e = (int)exs[node], eEnd = (int)exs[node + 1];
            float a0 = 0.f, a1 = 0.f;
            for (; e + 4 <= eEnd; e += 4) {
                uint2 p0 = payloadA[e0 + sidx[e]];
                uint2 p1 = payloadA[e0 + sidx[e + 1]];
                uint2 p2 = payloadA[e0 + sidx[e + 2]];
                uint2 p3 = payloadA[e0 + sidx[e + 3]];
                float s0 = x[(size_t)(p0.x >> BSHIFT) * DIM + d];
                float s1 = x[(size_t)(p1.x >> BSHIFT) * DIM + d];
                float s2 = x[(size_t)(p2.x >> BSHIFT) * DIM + d];
                float s3 = x[(size_t)(p3.x >> BSHIFT) * DIM + d];
                a0 += (s0 - xc) * __uint_as_float(p0.y);
                a1 += (s1 - xc) * __uint_as_float(p1.y);
                a0 += (s2 - xc) * __uint_as_float(p2.y);
                a1 += (s3 - xc) * __uint_as_float(p3.y);
            }
            for (; e < eEnd; ++e) {
                uint2 p = payloadA[e0 + sidx[e]];
                a0 += (x[(size_t)(p.x >> BSHIFT) * DIM + d] - xc) * __uint_as_float(p.y);
            }
            out[(size_t)gn * DIM + d] = a0 + a1 - xc;
        }
    } else {
        // overflow guard (statistically impossible): -x init + global atomics
        for (int slot = t; slot < NB * DIM; slot += 512) {
            int gn = b * NB + (slot >> 3);
            if (gn < N_NODES) {
                size_t gi = (size_t)b * NB * DIM + slot;
                out[gi] = -x[gi];
            }
        }
        __syncthreads();
        int d = t & 7, sub = t >> 3;
        for (int k = sub; k < n; k += 64) {
            uint2 p = payloadA[e0 + k];
            int node = (int)(p.x & (NB - 1));
            int r = (int)(p.x >> BSHIFT);
            int gn = b * NB + node;
            if (gn < N_NODES) {
                float xc = x[(size_t)gn * DIM + d];
                atomicAdd(&out[(size_t)gn * DIM + d],
                          (x[(size_t)r * DIM + d] - xc) * __uint_as_float(p.y));
            }
        }
    }
}

extern "C" void kernel_launch(void* const* d_in, const int* in_sizes, int n_in,
                              void* d_out, int out_size, void* d_ws, size_t ws_size,
                              hipStream_t stream) {
    const float* x   = (const float*)d_in[0];
    const int*   row = (const int*)d_in[1];
    const int*   col = (const int*)d_in[2];
    const float* w   = (const float*)d_in[3];
    float* out = (float*)d_out;
    int nE = in_sizes[1];
    int n4 = out_size / 4;

    int espan = (nE + G1 - 1) / G1;

    auto align256 = [](size_t v) { return (v + 255) & ~(size_t)255; };
    size_t off_payloadA  = 0;
    size_t off_L         = align256(off_payloadA + (size_t)nE * sizeof(uint2));
    size_t off_LT        = align256(off_L  + (size_t)G1 * LSROW * 4);
    size_t off_OT        = align256(off_LT + (size_t)LSROW * G1 * 4);
    size_t off_blockOffs = align256(off_OT + (size_t)NBUCKETS * G1 * 4);
    size_t off_total     = align256(off_blockOffs + (size_t)G1 * NBUCKETS * 4);
    size_t off_start     = align256(off_total + (size_t)NBUCKETS * 4);
    size_t need          = off_start + (size_t)(NBUCKETS + 1) * 4;

    if (ws_size < need || espan > ESPAN_MAX) {
        init_neg_kernel<<<(n4 + 255) / 256, 256, 0, stream>>>(x, out, n4);
        edge_scatter_atomic<<<(nE + 255) / 256, 256, 0, stream>>>(x, row, col, w, out, nE);
        return;
    }

    char* p = (char*)d_ws;
    uint2*    payloadA    = (uint2*)(p + off_payloadA);
    unsigned* L           = (unsigned*)(p + off_L);
    unsigned* LT          = (unsigned*)(p + off_LT);
    unsigned* OT          = (unsigned*)(p + off_OT);
    unsigned* blockOffs   = (unsigned*)(p + off_blockOffs);
    unsigned* bucketTotal = (unsigned*)(p + off_total);
    unsigned* bucketStart = (unsigned*)(p + off_start);

    hist_scan_kernel<<<G1, 256, 0, stream>>>(col, nE, espan, L);
    transpose_kernel<<<dim3((LSROW + 31) / 32, G1 / 32), dim3(32, 8), 0, stream>>>(
        L, LT, G1, LSROW);
    col_scan_kernel<<<NBUCKETS, 1024, 0, stream>>>(LT, OT, bucketTotal);
    bucket_scan_kernel<<<1, 1024, 0, stream>>>(bucketTotal, bucketStart);
    add_transpose_kernel<<<dim3(G1 / 32, (NBUCKETS + 31) / 32), dim3(32, 8), 0, stream>>>(
        OT, bucketStart, blockOffs);
    scatter2_kernel<<<G1, 512, 0, stream>>>(row, col, w, nE, espan, L,
                                            blockOffs, payloadA);
    bucket_sort_gather_kernel<<<NBUCKETS, 512, 0, stream>>>(x, payloadA,
                                                            bucketStart, out);
}

// Round 12
// 177.402 us; speedup vs baseline: 1.0163x; 1.0163x over previous
//
#include <hip/hip_runtime.h>

#define N_NODES 100000
#define DIM 8
#define NB 128                 // nodes per bucket
#define BSHIFT 7               // log2(NB)
#define NBUCKETS ((N_NODES + NB - 1) / NB)   // 782
#define LSROW (NBUCKETS + 1)   // 783 (local-scan row incl. sentinel)
#define G1 2048                // partition blocks
#define ESPAN_MAX 3328         // LDS stage cap for scatter
#define CAP 9300               // max edges per bucket (mean 8184, ~12 sigma)

// Wave-ballot group ranking: among the 64 lanes of this wave, find the group
// of lanes with equal `key` (NBITS bits). rank = position within group,
// cnt = group size, leader = highest active lane of group. Inactive lanes
// must pass a sentinel key that cannot equal any active key.
template<int NBITS>
__device__ __forceinline__ void wave_rank(unsigned key, bool act,
                                          unsigned& rank, unsigned& cnt,
                                          bool& leader) {
    unsigned long long m = ~0ull;
    #pragma unroll
    for (int i = 0; i < NBITS; ++i) {
        unsigned long long bal = __ballot((key >> i) & 1);
        m &= ((key >> i) & 1) ? bal : ~bal;
    }
    unsigned lane = threadIdx.x & 63u;
    unsigned long long lower = (1ull << lane) - 1ull;
    rank = (unsigned)__popcll(m & lower);
    cnt  = (unsigned)__popcll(m);
    leader = act && (rank == cnt - 1u);
}

// ---------------- fallback (atomic path) ----------------
__global__ void init_neg_kernel(const float* __restrict__ x,
                                float* __restrict__ out, int n4) {
    int i = blockIdx.x * blockDim.x + threadIdx.x;
    if (i < n4) {
        float4 v = reinterpret_cast<const float4*>(x)[i];
        float4 o; o.x = -v.x; o.y = -v.y; o.z = -v.z; o.w = -v.w;
        reinterpret_cast<float4*>(out)[i] = o;
    }
}

__global__ void edge_scatter_atomic(const float* __restrict__ x,
                                    const int* __restrict__ row,
                                    const int* __restrict__ col,
                                    const float* __restrict__ w,
                                    float* __restrict__ out, int nE) {
    int e = blockIdx.x * blockDim.x + threadIdx.x;
    if (e >= nE) return;
    int r = row[e], c = col[e];
    float we = w[e];
    const float4* xr = reinterpret_cast<const float4*>(x + (size_t)r * DIM);
    const float4* xc = reinterpret_cast<const float4*>(x + (size_t)c * DIM);
    float4 a0 = xr[0], a1 = xr[1], b0 = xc[0], b1 = xc[1];
    float* o = out + (size_t)c * DIM;
    atomicAdd(o + 0, (a0.x - b0.x) * we); atomicAdd(o + 1, (a0.y - b0.y) * we);
    atomicAdd(o + 2, (a0.z - b0.z) * we); atomicAdd(o + 3, (a0.w - b0.w) * we);
    atomicAdd(o + 4, (a1.x - b1.x) * we); atomicAdd(o + 5, (a1.y - b1.y) * we);
    atomicAdd(o + 6, (a1.z - b1.z) * we); atomicAdd(o + 7, (a1.w - b1.w) * we);
}

// ---------------- R12 pipeline ----------------

// K1: per-block histogram (ballot-ranked, no LDS atomics) + local exclusive
// scan, written coalesced as L[blk][0..781] (+ sentinel = n).
__global__ __launch_bounds__(256) void hist_scan_kernel(const int* __restrict__ col,
                                                        int nE, int espan,
                                                        unsigned* __restrict__ L) {
    __shared__ unsigned wcnt[4 * NBUCKETS];   // 12.5 KB (per-wave counts)
    __shared__ unsigned part[256];
    int t = threadIdx.x, blk = blockIdx.x;
    long e0 = (long)blk * espan;
    long rem = (long)nE - e0;
    int n = (int)(rem > (long)espan ? espan : (rem < 0 ? 0 : rem));

    for (int i = t; i < 4 * NBUCKETS; i += 256) wcnt[i] = 0;
    __syncthreads();

    int wv = t >> 6;
    int nceil = ((n + 255) >> 8) << 8;
    for (int kb = 0; kb < nceil; kb += 256) {
        int k = kb + t;
        bool act = k < n;
        unsigned c = 0;
        if (act) c = (unsigned)col[e0 + k];
        unsigned b = act ? (c >> BSHIFT) : 1023u;
        unsigned rank, cntg; bool leader;
        wave_rank<10>(b, act, rank, cntg, leader);
        if (leader) wcnt[wv * NBUCKETS + b] += cntg;   // plain RMW, wave-lockstep safe
    }
    __syncthreads();

    unsigned v[4], s = 0;
    #pragma unroll
    for (int j = 0; j < 4; ++j) {
        int b = 4 * t + j;
        v[j] = 0;
        if (b < NBUCKETS)
            v[j] = wcnt[b] + wcnt[NBUCKETS + b] + wcnt[2 * NBUCKETS + b] + wcnt[3 * NBUCKETS + b];
        s += v[j];
    }
    part[t] = s; __syncthreads();
    for (int off = 1; off < 256; off <<= 1) {
        unsigned u = (t >= off) ? part[t - off] : 0u;
        __syncthreads();
        part[t] += u; __syncthreads();
    }
    unsigned base = part[t] - s;
    size_t lrow = (size_t)blk * LSROW;
    #pragma unroll
    for (int j = 0; j < 4; ++j) {
        int b = 4 * t + j;
        if (b < NBUCKETS) { L[lrow + b] = base; base += v[j]; }
    }
    if (t == 255) L[lrow + NBUCKETS] = part[255];   // == n
}

// K2: tile transpose  in[R][C] -> out[C][R]
__global__ void transpose_kernel(const unsigned* __restrict__ in,
                                 unsigned* __restrict__ outp, int R, int C) {
    __shared__ unsigned tile[32][33];
    int tx = threadIdx.x, ty = threadIdx.y;
    int c0 = blockIdx.x * 32, r0 = blockIdx.y * 32;
    #pragma unroll
    for (int j = 0; j < 32; j += 8) {
        int r = r0 + ty + j, c = c0 + tx;
        if (r < R && c < C) tile[ty + j][tx] = in[(size_t)r * C + c];
    }
    __syncthreads();
    #pragma unroll
    for (int j = 0; j < 32; j += 8) {
        int c = c0 + ty + j, r = r0 + tx;
        if (r < R && c < C) outp[(size_t)c * R + r] = tile[tx][ty + j];
    }
}

// K3: per-bucket cross-block scan (coalesced rows of LT) -> OT, bucketTotal
__global__ __launch_bounds__(1024) void col_scan_kernel(const unsigned* __restrict__ LT,
                                                        unsigned* __restrict__ OT,
                                                        unsigned* __restrict__ bucketTotal) {
    __shared__ unsigned part[1024];
    int b = blockIdx.x, t = threadIdx.x;
    const unsigned* r0 = LT + (size_t)b * G1;
    const unsigned* r1 = LT + (size_t)(b + 1) * G1;
    unsigned c0 = r1[2 * t] - r0[2 * t];
    unsigned c1 = r1[2 * t + 1] - r0[2 * t + 1];
    part[t] = c0 + c1; __syncthreads();
    for (int off = 1; off < 1024; off <<= 1) {
        unsigned u = (t >= off) ? part[t - off] : 0u;
        __syncthreads();
        part[t] += u; __syncthreads();
    }
    unsigned ex = part[t] - (c0 + c1);
    OT[(size_t)b * G1 + 2 * t]     = ex;
    OT[(size_t)b * G1 + 2 * t + 1] = ex + c0;
    if (t == 1023) bucketTotal[b] = part[1023];
}

// K4: exclusive scan over bucket totals
__global__ __launch_bounds__(1024) void bucket_scan_kernel(const unsigned* __restrict__ bucketTotal,
                                                           unsigned* __restrict__ bucketStart) {
    __shared__ unsigned sc[1024];
    int t = threadIdx.x;
    unsigned v = (t < NBUCKETS) ? bucketTotal[t] : 0u;
    sc[t] = v; __syncthreads();
    for (int off = 1; off < 1024; off <<= 1) {
        unsigned u = (t >= off) ? sc[t - off] : 0u;
        __syncthreads();
        sc[t] += u; __syncthreads();
    }
    if (t < NBUCKETS) bucketStart[t] = sc[t] - v;
    if (t == NBUCKETS - 1) bucketStart[NBUCKETS] = sc[t];
}

// K5: blockOffs[blk][b] = OT[b][blk] + bucketStart[b]  (tile transpose)
__global__ void add_transpose_kernel(const unsigned* __restrict__ OT,
                                     const unsigned* __restrict__ bucketStart,
                                     unsigned* __restrict__ blockOffs) {
    __shared__ unsigned tile[32][33];
    int tx = threadIdx.x, ty = threadIdx.y;
    int blk0 = blockIdx.x * 32, b0 = blockIdx.y * 32;
    #pragma unroll
    for (int j = 0; j < 32; j += 8) {
        int b = b0 + ty + j, blk = blk0 + tx;
        if (b < NBUCKETS && blk < G1)
            tile[ty + j][tx] = OT[(size_t)b * G1 + blk] + bucketStart[b];
    }
    __syncthreads();
    #pragma unroll
    for (int j = 0; j < 32; j += 8) {
        int blk = blk0 + ty + j, b = b0 + tx;
        if (b < NBUCKETS && blk < G1)
            blockOffs[(size_t)blk * NBUCKETS + b] = tile[tx][ty + j];
    }
}

// K6: local counting sort via ballot-rank + per-wave u16 cursors (no LDS
// atomics), then coalesced run-flush to bucket-major payloadA.
__global__ __launch_bounds__(512) void scatter3_kernel(
        const int* __restrict__ row,
        const int* __restrict__ col,
        const float* __restrict__ w,
        int nE, int espan,
        const unsigned* __restrict__ L,
        const unsigned* __restrict__ blockOffs,
        uint2* __restrict__ payloadA) {
    __shared__ uint2 stage[ESPAN_MAX];             // 26.6 KB
    __shared__ unsigned short sbkt[ESPAN_MAX];     // 6.7 KB
    __shared__ unsigned short wcur[8 * NBUCKETS];  // 12.5 KB (counts -> cursors, u16: espan<65536)
    __shared__ unsigned diff[NBUCKETS];            // 3.1 KB
    int t = threadIdx.x, blk = blockIdx.x;
    long e0 = (long)blk * espan;
    long rem = (long)nE - e0;
    int n = (int)(rem > (long)espan ? espan : (rem < 0 ? 0 : rem));
    size_t lrow = (size_t)blk * LSROW;
    int wv = t >> 6;

    for (int i = t; i < 8 * NBUCKETS; i += 512) wcur[i] = 0;
    __syncthreads();

    // pass 1: per-wave counts via ballot rank
    int nceil = ((n + 511) >> 9) << 9;
    for (int kb = 0; kb < nceil; kb += 512) {
        int k = kb + t;
        bool act = k < n;
        unsigned c = 0;
        if (act) c = (unsigned)col[e0 + k];
        unsigned b = act ? (c >> BSHIFT) : 1023u;
        unsigned rank, cntg; bool leader;
        wave_rank<10>(b, act, rank, cntg, leader);
        if (leader) wcur[wv * NBUCKETS + b] = (unsigned short)(wcur[wv * NBUCKETS + b] + cntg);
    }
    __syncthreads();

    // scan: per-bucket cross-wave exclusive prefix (+ local start from L),
    // also build diff[b] = globalBase - localStart for the flush.
    for (int b = t; b < NBUCKETS; b += 512) {
        unsigned lv = L[lrow + b];
        diff[b] = blockOffs[(size_t)blk * NBUCKETS + b] - lv;
        unsigned base = lv;
        #pragma unroll
        for (int wj = 0; wj < 8; ++wj) {
            unsigned tmp = wcur[wj * NBUCKETS + b];
            wcur[wj * NBUCKETS + b] = (unsigned short)base;
            base += tmp;
        }
    }
    __syncthreads();

    // pass 2: place into LDS stage via ballot rank + per-wave cursor
    for (int kb = 0; kb < nceil; kb += 512) {
        int k = kb + t;
        bool act = k < n;
        unsigned c = 0, r = 0; float wt = 0.f;
        if (act) {
            c  = (unsigned)col[e0 + k];
            r  = (unsigned)row[e0 + k];
            wt = w[e0 + k];
        }
        unsigned b = act ? (c >> BSHIFT) : 1023u;
        unsigned rank, cntg; bool leader;
        wave_rank<10>(b, act, rank, cntg, leader);
        unsigned base = 0;
        if (act) base = wcur[wv * NBUCKETS + b];
        if (leader) wcur[wv * NBUCKETS + b] = (unsigned short)(base + cntg);
        if (act) {
            unsigned pos = base + rank;
            stage[pos] = make_uint2((r << BSHIFT) | (c & (NB - 1)), __float_as_uint(wt));
            sbkt[pos] = (unsigned short)b;
        }
    }
    __syncthreads();

    // flush: per-bucket runs -> bucket-major global positions (run-coalesced)
    for (int k = t; k < n; k += 512) {
        unsigned b = sbkt[k];
        payloadA[diff[b] + (unsigned)k] = stage[k];
    }
}

// K7 (fused): per-bucket node sort via ballot-rank into uint2 LDS stage,
// then register gather -> out. No global atomics, no payloadB.
__global__ __launch_bounds__(512) void bucket_sort_gather_kernel(
        const float* __restrict__ x,
        const uint2* __restrict__ payloadA,
        const unsigned* __restrict__ bucketStart,
        float* __restrict__ out) {
    __shared__ uint2 stage[CAP];            // 72.7 KB
    __shared__ unsigned wcur[8 * NB];       // 4 KB (per-wave counts -> cursors)
    __shared__ unsigned cnt[NB];
    __shared__ unsigned scanb[NB];
    __shared__ unsigned exs[NB + 1];
    int b = blockIdx.x, t = threadIdx.x;
    int e0 = (int)bucketStart[b], e1 = (int)bucketStart[b + 1];
    int n = e1 - e0;
    int wv = t >> 6;

    if (n <= CAP) {
        for (int i = t; i < 8 * NB; i += 512) wcur[i] = 0;
        __syncthreads();

        // pass 1: per-wave node counts via ballot rank
        int nceil = ((n + 511) >> 9) << 9;
        for (int kb = 0; kb < nceil; kb += 512) {
            int k = kb + t;
            bool act = k < n;
            unsigned key = 255u;
            if (act) key = payloadA[e0 + k].x & (NB - 1);
            unsigned rank, cntg; bool leader;
            wave_rank<8>(key, act, rank, cntg, leader);
            if (leader) wcur[wv * NB + key] += cntg;
        }
        __syncthreads();

        // scan: per-node totals + 128-wide exclusive scan + per-wave bases
        if (t < NB) {
            unsigned s = 0;
            #pragma unroll
            for (int wj = 0; wj < 8; ++wj) s += wcur[wj * NB + t];
            cnt[t] = s;
            scanb[t] = s;
        }
        __syncthreads();
        for (int off = 1; off < NB; off <<= 1) {
            unsigned v = 0;
            if (t < NB && t >= off) v = scanb[t - off];
            __syncthreads();
            if (t < NB) scanb[t] += v;
            __syncthreads();
        }
        if (t < NB) {
            unsigned ex = scanb[t] - cnt[t];
            exs[t] = ex;
            unsigned base = ex;
            #pragma unroll
            for (int wj = 0; wj < 8; ++wj) {
                unsigned tmp = wcur[wj * NB + t];
                wcur[wj * NB + t] = base;
                base += tmp;
            }
        }
        if (t == 0) exs[NB] = (unsigned)n;
        __syncthreads();

        // pass 2: place (row, w) into stage sorted by node
        for (int kb = 0; kb < nceil; kb += 512) {
            int k = kb + t;
            bool act = k < n;
            uint2 p = make_uint2(0u, 0u);
            unsigned key = 255u;
            if (act) {
                p = payloadA[e0 + k];
                key = p.x & (NB - 1);
            }
            unsigned rank, cntg; bool leader;
            wave_rank<8>(key, act, rank, cntg, leader);
            unsigned base = 0;
            if (act) base = wcur[wv * NB + key];
            if (leader) wcur[wv * NB + key] = base + cntg;
            if (act)
                stage[base + rank] = make_uint2(p.x >> BSHIFT, p.y);
        }
        __syncthreads();

        // register gather from LDS stage; out = acc - x, coalesced write
        for (int slot = t; slot < NB * DIM; slot += 512) {
            int node = slot >> 3, d = slot & 7;
            int gn = b * NB + node;
            if (gn >= N_NODES) continue;
            float xc = x[(size_t)gn * DIM + d];
            int e = (int)exs[node], eEnd = (int)exs[node + 1];
            float a0 = 0.f, a1 = 0.f;
            for (; e + 4 <= eEnd; e += 4) {
                uint2 p0 = stage[e];
                uint2 p1 = stage[e + 1];
                uint2 p2 = stage[e + 2];
                uint2 p3 = stage[e + 3];
                float s0 = x[(size_t)p0.x * DIM + d];
                float s1 = x[(size_t)p1.x * DIM + d];
                float s2 = x[(size_t)p2.x * DIM + d];
                float s3 = x[(size_t)p3.x * DIM + d];
                a0 += (s0 - xc) * __uint_as_float(p0.y);
                a1 += (s1 - xc) * __uint_as_float(p1.y);
                a0 += (s2 - xc) * __uint_as_float(p2.y);
                a1 += (s3 - xc) * __uint_as_float(p3.y);
            }
            for (; e < eEnd; ++e) {
                uint2 p = stage[e];
                a0 += (x[(size_t)p.x * DIM + d] - xc) * __uint_as_float(p.y);
            }
            out[(size_t)gn * DIM + d] = a0 + a1 - xc;
        }
    } else {
        // overflow guard (statistically impossible): -x init + global atomics
        for (int slot = t; slot < NB * DIM; slot += 512) {
            int gn = b * NB + (slot >> 3);
            if (gn < N_NODES) {
                size_t gi = (size_t)b * NB * DIM + slot;
                out[gi] = -x[gi];
            }
        }
        __syncthreads();
        int d = t & 7, sub = t >> 3;
        for (int k = sub; k < n; k += 64) {
            uint2 p = payloadA[e0 + k];
            int node = (int)(p.x & (NB - 1));
            int r = (int)(p.x >> BSHIFT);
            int gn = b * NB + node;
            if (gn < N_NODES) {
                float xc = x[(size_t)gn * DIM + d];
                atomicAdd(&out[(size_t)gn * DIM + d],
                          (x[(size_t)r * DIM + d] - xc) * __uint_as_float(p.y));
            }
        }
    }
}

extern "C" void kernel_launch(void* const* d_in, const int* in_sizes, int n_in,
                              void* d_out, int out_size, void* d_ws, size_t ws_size,
                              hipStream_t stream) {
    const float* x   = (const float*)d_in[0];
    const int*   row = (const int*)d_in[1];
    const int*   col = (const int*)d_in[2];
    const float* w   = (const float*)d_in[3];
    float* out = (float*)d_out;
    int nE = in_sizes[1];
    int n4 = out_size / 4;

    int espan = (nE + G1 - 1) / G1;

    auto align256 = [](size_t v) { return (v + 255) & ~(size_t)255; };
    size_t off_payloadA  = 0;
    size_t off_L         = align256(off_payloadA + (size_t)nE * sizeof(uint2));
    size_t off_LT        = align256(off_L  + (size_t)G1 * LSROW * 4);
    size_t off_OT        = align256(off_LT + (size_t)LSROW * G1 * 4);
    size_t off_blockOffs = align256(off_OT + (size_t)NBUCKETS * G1 * 4);
    size_t off_total     = align256(off_blockOffs + (size_t)G1 * NBUCKETS * 4);
    size_t off_start     = align256(off_total + (size_t)NBUCKETS * 4);
    size_t need          = off_start + (size_t)(NBUCKETS + 1) * 4;

    if (ws_size < need || espan > ESPAN_MAX) {
        init_neg_kernel<<<(n4 + 255) / 256, 256, 0, stream>>>(x, out, n4);
        edge_scatter_atomic<<<(nE + 255) / 256, 256, 0, stream>>>(x, row, col, w, out, nE);
        return;
    }

    char* p = (char*)d_ws;
    uint2*    payloadA    = (uint2*)(p + off_payloadA);
    unsigned* L           = (unsigned*)(p + off_L);
    unsigned* LT          = (unsigned*)(p + off_LT);
    unsigned* OT          = (unsigned*)(p + off_OT);
    unsigned* blockOffs   = (unsigned*)(p + off_blockOffs);
    unsigned* bucketTotal = (unsigned*)(p + off_total);
    unsigned* bucketStart = (unsigned*)(p + off_start);

    hist_scan_kernel<<<G1, 256, 0, stream>>>(col, nE, espan, L);
    transpose_kernel<<<dim3((LSROW + 31) / 32, G1 / 32), dim3(32, 8), 0, stream>>>(
        L, LT, G1, LSROW);
    col_scan_kernel<<<NBUCKETS, 1024, 0, stream>>>(LT, OT, bucketTotal);
    bucket_scan_kernel<<<1, 1024, 0, stream>>>(bucketTotal, bucketStart);
    add_transpose_kernel<<<dim3(G1 / 32, (NBUCKETS + 31) / 32), dim3(32, 8), 0, stream>>>(
        OT, bucketStart, blockOffs);
    scatter3_kernel<<<G1, 512, 0, stream>>>(row, col, w, nE, espan, L,
                                            blockOffs, payloadA);
    bucket_sort_gather_kernel<<<NBUCKETS, 512, 0, stream>>>(x, payloadA,
                                                            bucketStart, out);
}

// Round 13
// 123.023 us; speedup vs baseline: 1.4655x; 1.4420x over previous
//
#include <hip/hip_runtime.h>

#define N_NODES 100000
#define DIM 8
#define NB 128                 // nodes per bucket
#define BSHIFT 7               // log2(NB)
#define NBUCKETS ((N_NODES + NB - 1) / NB)   // 782
#define LSROW (NBUCKETS + 1)   // 783 (local-scan row incl. sentinel)
#define G1 2048                // partition blocks
#define ESPAN_MAX 3328         // LDS stage cap for scatter
#define CAP 9728               // max edges per bucket (mean 8184, ~17 sigma)

// ---------------- fallback (atomic path) ----------------
__global__ void init_neg_kernel(const float* __restrict__ x,
                                float* __restrict__ out, int n4) {
    int i = blockIdx.x * blockDim.x + threadIdx.x;
    if (i < n4) {
        float4 v = reinterpret_cast<const float4*>(x)[i];
        float4 o; o.x = -v.x; o.y = -v.y; o.z = -v.z; o.w = -v.w;
        reinterpret_cast<float4*>(out)[i] = o;
    }
}

__global__ void edge_scatter_atomic(const float* __restrict__ x,
                                    const int* __restrict__ row,
                                    const int* __restrict__ col,
                                    const float* __restrict__ w,
                                    float* __restrict__ out, int nE) {
    int e = blockIdx.x * blockDim.x + threadIdx.x;
    if (e >= nE) return;
    int r = row[e], c = col[e];
    float we = w[e];
    const float4* xr = reinterpret_cast<const float4*>(x + (size_t)r * DIM);
    const float4* xc = reinterpret_cast<const float4*>(x + (size_t)c * DIM);
    float4 a0 = xr[0], a1 = xr[1], b0 = xc[0], b1 = xc[1];
    float* o = out + (size_t)c * DIM;
    atomicAdd(o + 0, (a0.x - b0.x) * we); atomicAdd(o + 1, (a0.y - b0.y) * we);
    atomicAdd(o + 2, (a0.z - b0.z) * we); atomicAdd(o + 3, (a0.w - b0.w) * we);
    atomicAdd(o + 4, (a1.x - b1.x) * we); atomicAdd(o + 5, (a1.y - b1.y) * we);
    atomicAdd(o + 6, (a1.z - b1.z) * we); atomicAdd(o + 7, (a1.w - b1.w) * we);
}

// ---------------- R13 pipeline (R10 + 1024-thread K7) ----------------

// K1: per-block histogram + LOCAL exclusive scan, coalesced L[blk][0..782]
__global__ __launch_bounds__(256) void hist_scan_kernel(const int* __restrict__ col,
                                                        int nE, int espan,
                                                        unsigned* __restrict__ L) {
    __shared__ unsigned cnt[NBUCKETS];
    __shared__ unsigned part[256];
    int t = threadIdx.x, blk = blockIdx.x;
    long e0 = (long)blk * espan;
    long rem = (long)nE - e0;
    int n = (int)(rem > (long)espan ? espan : (rem < 0 ? 0 : rem));

    for (int i = t; i < NBUCKETS; i += 256) cnt[i] = 0;
    __syncthreads();
    for (int k = t; k < n; k += 256)
        atomicAdd(&cnt[((unsigned)col[e0 + k]) >> BSHIFT], 1u);
    __syncthreads();

    unsigned v[4], s = 0;
    #pragma unroll
    for (int j = 0; j < 4; ++j) {
        int b = 4 * t + j;
        v[j] = (b < NBUCKETS) ? cnt[b] : 0u;
        s += v[j];
    }
    part[t] = s; __syncthreads();
    for (int off = 1; off < 256; off <<= 1) {
        unsigned u = (t >= off) ? part[t - off] : 0u;
        __syncthreads();
        part[t] += u; __syncthreads();
    }
    unsigned base = part[t] - s;
    size_t lrow = (size_t)blk * LSROW;
    #pragma unroll
    for (int j = 0; j < 4; ++j) {
        int b = 4 * t + j;
        if (b < NBUCKETS) { L[lrow + b] = base; base += v[j]; }
    }
    if (t == 255) L[lrow + NBUCKETS] = part[255];   // == n
}

// K2: tile transpose  in[R][C] -> out[C][R]
__global__ void transpose_kernel(const unsigned* __restrict__ in,
                                 unsigned* __restrict__ outp, int R, int C) {
    __shared__ unsigned tile[32][33];
    int tx = threadIdx.x, ty = threadIdx.y;
    int c0 = blockIdx.x * 32, r0 = blockIdx.y * 32;
    #pragma unroll
    for (int j = 0; j < 32; j += 8) {
        int r = r0 + ty + j, c = c0 + tx;
        if (r < R && c < C) tile[ty + j][tx] = in[(size_t)r * C + c];
    }
    __syncthreads();
    #pragma unroll
    for (int j = 0; j < 32; j += 8) {
        int c = c0 + ty + j, r = r0 + tx;
        if (r < R && c < C) outp[(size_t)c * R + r] = tile[tx][ty + j];
    }
}

// K3: per-bucket cross-block scan (coalesced rows of LT) -> OT, bucketTotal
__global__ __launch_bounds__(1024) void col_scan_kernel(const unsigned* __restrict__ LT,
                                                        unsigned* __restrict__ OT,
                                                        unsigned* __restrict__ bucketTotal) {
    __shared__ unsigned part[1024];
    int b = blockIdx.x, t = threadIdx.x;
    const unsigned* r0 = LT + (size_t)b * G1;
    const unsigned* r1 = LT + (size_t)(b + 1) * G1;
    unsigned c0 = r1[2 * t] - r0[2 * t];
    unsigned c1 = r1[2 * t + 1] - r0[2 * t + 1];
    part[t] = c0 + c1; __syncthreads();
    for (int off = 1; off < 1024; off <<= 1) {
        unsigned u = (t >= off) ? part[t - off] : 0u;
        __syncthreads();
        part[t] += u; __syncthreads();
    }
    unsigned ex = part[t] - (c0 + c1);
    OT[(size_t)b * G1 + 2 * t]     = ex;
    OT[(size_t)b * G1 + 2 * t + 1] = ex + c0;
    if (t == 1023) bucketTotal[b] = part[1023];
}

// K4: exclusive scan over bucket totals
__global__ __launch_bounds__(1024) void bucket_scan_kernel(const unsigned* __restrict__ bucketTotal,
                                                           unsigned* __restrict__ bucketStart) {
    __shared__ unsigned sc[1024];
    int t = threadIdx.x;
    unsigned v = (t < NBUCKETS) ? bucketTotal[t] : 0u;
    sc[t] = v; __syncthreads();
    for (int off = 1; off < 1024; off <<= 1) {
        unsigned u = (t >= off) ? sc[t - off] : 0u;
        __syncthreads();
        sc[t] += u; __syncthreads();
    }
    if (t < NBUCKETS) bucketStart[t] = sc[t] - v;
    if (t == NBUCKETS - 1) bucketStart[NBUCKETS] = sc[t];
}

// K5: blockOffs[blk][b] = OT[b][blk] + bucketStart[b]  (tile transpose)
__global__ void add_transpose_kernel(const unsigned* __restrict__ OT,
                                     const unsigned* __restrict__ bucketStart,
                                     unsigned* __restrict__ blockOffs) {
    __shared__ unsigned tile[32][33];
    int tx = threadIdx.x, ty = threadIdx.y;
    int blk0 = blockIdx.x * 32, b0 = blockIdx.y * 32;
    #pragma unroll
    for (int j = 0; j < 32; j += 8) {
        int b = b0 + ty + j, blk = blk0 + tx;
        if (b < NBUCKETS && blk < G1)
            tile[ty + j][tx] = OT[(size_t)b * G1 + blk] + bucketStart[b];
    }
    __syncthreads();
    #pragma unroll
    for (int j = 0; j < 32; j += 8) {
        int blk = blk0 + ty + j, b = b0 + tx;
        if (b < NBUCKETS && blk < G1)
            blockOffs[(size_t)blk * NBUCKETS + b] = tile[tx][ty + j];
    }
}

// K6: single-pass local sort + coalesced run-flush (39.5 KB LDS)
__global__ __launch_bounds__(512) void scatter2_kernel(
        const int* __restrict__ row,
        const int* __restrict__ col,
        const float* __restrict__ w,
        int nE, int espan,
        const unsigned* __restrict__ L,
        const unsigned* __restrict__ blockOffs,
        uint2* __restrict__ payloadA) {
    __shared__ uint2 stage[ESPAN_MAX];           // 26.6 KB
    __shared__ unsigned short sbkt[ESPAN_MAX];   // 6.7 KB
    __shared__ unsigned cur[NBUCKETS];           // 3.1 KB
    __shared__ unsigned diff[NBUCKETS];          // 3.1 KB
    int t = threadIdx.x, blk = blockIdx.x;
    long e0 = (long)blk * espan;
    long rem = (long)nE - e0;
    int n = (int)(rem > (long)espan ? espan : (rem < 0 ? 0 : rem));
    size_t lrow = (size_t)blk * LSROW;

    for (int i = t; i < NBUCKETS; i += 512) {
        unsigned lv = L[lrow + i];
        cur[i]  = lv;
        diff[i] = blockOffs[(size_t)blk * NBUCKETS + i] - lv;
    }
    __syncthreads();

    for (int k = t; k < n; k += 512) {
        unsigned c = (unsigned)col[e0 + k];
        unsigned b = c >> BSHIFT;
        unsigned pos = atomicAdd(&cur[b], 1u);
        stage[pos] = make_uint2(((unsigned)row[e0 + k] << BSHIFT) | (c & (NB - 1)),
                                __float_as_uint(w[e0 + k]));
        sbkt[pos] = (unsigned short)b;
    }
    __syncthreads();

    for (int k = t; k < n; k += 512) {
        unsigned b = sbkt[k];
        payloadA[diff[b] + (unsigned)k] = stage[k];
    }
}

// K7 (fused, 1024 threads): per-bucket in-LDS node sort + register gather.
// LDS ~78 KB -> 2 blocks/CU x 1024 thr = 32 waves/CU (was 16 at 512 thr).
__global__ __launch_bounds__(1024) void bucket_sort_gather_kernel(
        const float* __restrict__ x,
        const uint2* __restrict__ payloadA,
        const unsigned* __restrict__ bucketStart,
        float* __restrict__ out) {
    __shared__ uint2 stage[CAP];          // 76 KB
    __shared__ unsigned cnt[NB];
    __shared__ unsigned scanb[NB];
    __shared__ unsigned exs[NB + 1];
    int b = blockIdx.x, t = threadIdx.x;
    int e0 = (int)bucketStart[b], e1 = (int)bucketStart[b + 1];
    int n = e1 - e0;

    if (t < NB) cnt[t] = 0;
    __syncthreads();

    if (n <= CAP) {
        for (int k = t; k < n; k += 1024)
            atomicAdd(&cnt[payloadA[e0 + k].x & (NB - 1)], 1u);
        __syncthreads();
        if (t < NB) scanb[t] = cnt[t];
        __syncthreads();
        for (int off = 1; off < NB; off <<= 1) {
            unsigned v = 0;
            if (t < NB && t >= off) v = scanb[t - off];
            __syncthreads();
            if (t < NB) scanb[t] += v;
            __syncthreads();
        }
        if (t < NB) {
            unsigned ex = scanb[t] - cnt[t];
            exs[t] = ex;
            cnt[t] = ex;                  // cursor
        }
        if (t == 0) exs[NB] = (unsigned)n;
        __syncthreads();

        for (int k = t; k < n; k += 1024) {
            uint2 p = payloadA[e0 + k];
            unsigned node = p.x & (NB - 1);
            unsigned pos = atomicAdd(&cnt[node], 1u);
            stage[pos] = make_uint2(p.x >> BSHIFT, p.y);
        }
        __syncthreads();

        // 1024 slots, 1024 threads: one (node,dim) per thread
        int slot = t;
        int node = slot >> 3, d = slot & 7;
        int gn = b * NB + node;
        if (gn < N_NODES) {
            float xc = x[(size_t)gn * DIM + d];
            int e = (int)exs[node], eEnd = (int)exs[node + 1];
            float a0 = 0.f, a1 = 0.f;
            for (; e + 4 <= eEnd; e += 4) {
                uint2 p0 = stage[e];
                uint2 p1 = stage[e + 1];
                uint2 p2 = stage[e + 2];
                uint2 p3 = stage[e + 3];
                float s0 = x[(size_t)p0.x * DIM + d];
                float s1 = x[(size_t)p1.x * DIM + d];
                float s2 = x[(size_t)p2.x * DIM + d];
                float s3 = x[(size_t)p3.x * DIM + d];
                a0 += (s0 - xc) * __uint_as_float(p0.y);
                a1 += (s1 - xc) * __uint_as_float(p1.y);
                a0 += (s2 - xc) * __uint_as_float(p2.y);
                a1 += (s3 - xc) * __uint_as_float(p3.y);
            }
            for (; e < eEnd; ++e) {
                uint2 p = stage[e];
                a0 += (x[(size_t)p.x * DIM + d] - xc) * __uint_as_float(p.y);
            }
            out[(size_t)gn * DIM + d] = a0 + a1 - xc;
        }
    } else {
        // overflow guard (statistically impossible): -x init + global atomics
        for (int slot = t; slot < NB * DIM; slot += 1024) {
            int gn = b * NB + (slot >> 3);
            if (gn < N_NODES) {
                size_t gi = (size_t)b * NB * DIM + slot;
                out[gi] = -x[gi];
            }
        }
        __syncthreads();
        int d = t & 7, sub = t >> 3;
        for (int k = sub; k < n; k += 128) {
            uint2 p = payloadA[e0 + k];
            int node = (int)(p.x & (NB - 1));
            int r = (int)(p.x >> BSHIFT);
            int gn = b * NB + node;
            if (gn < N_NODES) {
                float xc = x[(size_t)gn * DIM + d];
                atomicAdd(&out[(size_t)gn * DIM + d],
                          (x[(size_t)r * DIM + d] - xc) * __uint_as_float(p.y));
            }
        }
    }
}

extern "C" void kernel_launch(void* const* d_in, const int* in_sizes, int n_in,
                              void* d_out, int out_size, void* d_ws, size_t ws_size,
                              hipStream_t stream) {
    const float* x   = (const float*)d_in[0];
    const int*   row = (const int*)d_in[1];
    const int*   col = (const int*)d_in[2];
    const float* w   = (const float*)d_in[3];
    float* out = (float*)d_out;
    int nE = in_sizes[1];
    int n4 = out_size / 4;

    int espan = (nE + G1 - 1) / G1;

    auto align256 = [](size_t v) { return (v + 255) & ~(size_t)255; };
    size_t off_payloadA  = 0;
    size_t off_L         = align256(off_payloadA + (size_t)nE * sizeof(uint2));
    size_t off_LT        = align256(off_L  + (size_t)G1 * LSROW * 4);
    size_t off_OT        = align256(off_LT + (size_t)LSROW * G1 * 4);
    size_t off_blockOffs = align256(off_OT + (size_t)NBUCKETS * G1 * 4);
    size_t off_total     = align256(off_blockOffs + (size_t)G1 * NBUCKETS * 4);
    size_t off_start     = align256(off_total + (size_t)NBUCKETS * 4);
    size_t need          = off_start + (size_t)(NBUCKETS + 1) * 4;

    if (ws_size < need || espan > ESPAN_MAX) {
        init_neg_kernel<<<(n4 + 255) / 256, 256, 0, stream>>>(x, out, n4);
        edge_scatter_atomic<<<(nE + 255) / 256, 256, 0, stream>>>(x, row, col, w, out, nE);
        return;
    }

    char* p = (char*)d_ws;
    uint2*    payloadA    = (uint2*)(p + off_payloadA);
    unsigned* L           = (unsigned*)(p + off_L);
    unsigned* LT          = (unsigned*)(p + off_LT);
    unsigned* OT          = (unsigned*)(p + off_OT);
    unsigned* blockOffs   = (unsigned*)(p + off_blockOffs);
    unsigned* bucketTotal = (unsigned*)(p + off_total);
    unsigned* bucketStart = (unsigned*)(p + off_start);

    hist_scan_kernel<<<G1, 256, 0, stream>>>(col, nE, espan, L);
    transpose_kernel<<<dim3((LSROW + 31) / 32, G1 / 32), dim3(32, 8), 0, stream>>>(
        L, LT, G1, LSROW);
    col_scan_kernel<<<NBUCKETS, 1024, 0, stream>>>(LT, OT, bucketTotal);
    bucket_scan_kernel<<<1, 1024, 0, stream>>>(bucketTotal, bucketStart);
    add_transpose_kernel<<<dim3(G1 / 32, (NBUCKETS + 31) / 32), dim3(32, 8), 0, stream>>>(
        OT, bucketStart, blockOffs);
    scatter2_kernel<<<G1, 512, 0, stream>>>(row, col, w, nE, espan, L,
                                            blockOffs, payloadA);
    bucket_sort_gather_kernel<<<NBUCKETS, 1024, 0, stream>>>(x, payloadA,
                                                             bucketStart, out);
}

// Round 14
// 109.940 us; speedup vs baseline: 1.6399x; 1.1190x over previous
//
#include <hip/hip_runtime.h>

#define N_NODES 100000
#define DIM 8
#define NB 128                 // nodes per bucket
#define BSHIFT 7               // log2(NB)
#define NBUCKETS ((N_NODES + NB - 1) / NB)   // 782
#define LSROW (NBUCKETS + 1)   // 783 (local-scan row incl. sentinel)
#define G1 2048                // partition blocks
#define ESPAN_MAX 3328         // LDS stage cap for scatter
#define CAP 9728               // max edges per bucket (mean 8184, ~17 sigma)

// ---------------- fallback (atomic path) ----------------
__global__ void init_neg_kernel(const float* __restrict__ x,
                                float* __restrict__ out, int n4) {
    int i = blockIdx.x * blockDim.x + threadIdx.x;
    if (i < n4) {
        float4 v = reinterpret_cast<const float4*>(x)[i];
        float4 o; o.x = -v.x; o.y = -v.y; o.z = -v.z; o.w = -v.w;
        reinterpret_cast<float4*>(out)[i] = o;
    }
}

__global__ void edge_scatter_atomic(const float* __restrict__ x,
                                    const int* __restrict__ row,
                                    const int* __restrict__ col,
                                    const float* __restrict__ w,
                                    float* __restrict__ out, int nE) {
    int e = blockIdx.x * blockDim.x + threadIdx.x;
    if (e >= nE) return;
    int r = row[e], c = col[e];
    float we = w[e];
    const float4* xr = reinterpret_cast<const float4*>(x + (size_t)r * DIM);
    const float4* xc = reinterpret_cast<const float4*>(x + (size_t)c * DIM);
    float4 a0 = xr[0], a1 = xr[1], b0 = xc[0], b1 = xc[1];
    float* o = out + (size_t)c * DIM;
    atomicAdd(o + 0, (a0.x - b0.x) * we); atomicAdd(o + 1, (a0.y - b0.y) * we);
    atomicAdd(o + 2, (a0.z - b0.z) * we); atomicAdd(o + 3, (a0.w - b0.w) * we);
    atomicAdd(o + 4, (a1.x - b1.x) * we); atomicAdd(o + 5, (a1.y - b1.y) * we);
    atomicAdd(o + 6, (a1.z - b1.z) * we); atomicAdd(o + 7, (a1.w - b1.w) * we);
}

// ---------------- R14 pipeline (R13 + XCD-chunked scatter swizzle) ----------------

// K1: per-block histogram + LOCAL exclusive scan, coalesced L[blk][0..782]
__global__ __launch_bounds__(256) void hist_scan_kernel(const int* __restrict__ col,
                                                        int nE, int espan,
                                                        unsigned* __restrict__ L) {
    __shared__ unsigned cnt[NBUCKETS];
    __shared__ unsigned part[256];
    int t = threadIdx.x, blk = blockIdx.x;
    long e0 = (long)blk * espan;
    long rem = (long)nE - e0;
    int n = (int)(rem > (long)espan ? espan : (rem < 0 ? 0 : rem));

    for (int i = t; i < NBUCKETS; i += 256) cnt[i] = 0;
    __syncthreads();
    for (int k = t; k < n; k += 256)
        atomicAdd(&cnt[((unsigned)col[e0 + k]) >> BSHIFT], 1u);
    __syncthreads();

    unsigned v[4], s = 0;
    #pragma unroll
    for (int j = 0; j < 4; ++j) {
        int b = 4 * t + j;
        v[j] = (b < NBUCKETS) ? cnt[b] : 0u;
        s += v[j];
    }
    part[t] = s; __syncthreads();
    for (int off = 1; off < 256; off <<= 1) {
        unsigned u = (t >= off) ? part[t - off] : 0u;
        __syncthreads();
        part[t] += u; __syncthreads();
    }
    unsigned base = part[t] - s;
    size_t lrow = (size_t)blk * LSROW;
    #pragma unroll
    for (int j = 0; j < 4; ++j) {
        int b = 4 * t + j;
        if (b < NBUCKETS) { L[lrow + b] = base; base += v[j]; }
    }
    if (t == 255) L[lrow + NBUCKETS] = part[255];   // == n
}

// K2: tile transpose  in[R][C] -> out[C][R]
__global__ void transpose_kernel(const unsigned* __restrict__ in,
                                 unsigned* __restrict__ outp, int R, int C) {
    __shared__ unsigned tile[32][33];
    int tx = threadIdx.x, ty = threadIdx.y;
    int c0 = blockIdx.x * 32, r0 = blockIdx.y * 32;
    #pragma unroll
    for (int j = 0; j < 32; j += 8) {
        int r = r0 + ty + j, c = c0 + tx;
        if (r < R && c < C) tile[ty + j][tx] = in[(size_t)r * C + c];
    }
    __syncthreads();
    #pragma unroll
    for (int j = 0; j < 32; j += 8) {
        int c = c0 + ty + j, r = r0 + tx;
        if (r < R && c < C) outp[(size_t)c * R + r] = tile[tx][ty + j];
    }
}

// K3: per-bucket cross-block scan (coalesced rows of LT) -> OT, bucketTotal
__global__ __launch_bounds__(1024) void col_scan_kernel(const unsigned* __restrict__ LT,
                                                        unsigned* __restrict__ OT,
                                                        unsigned* __restrict__ bucketTotal) {
    __shared__ unsigned part[1024];
    int b = blockIdx.x, t = threadIdx.x;
    const unsigned* r0 = LT + (size_t)b * G1;
    const unsigned* r1 = LT + (size_t)(b + 1) * G1;
    unsigned c0 = r1[2 * t] - r0[2 * t];
    unsigned c1 = r1[2 * t + 1] - r0[2 * t + 1];
    part[t] = c0 + c1; __syncthreads();
    for (int off = 1; off < 1024; off <<= 1) {
        unsigned u = (t >= off) ? part[t - off] : 0u;
        __syncthreads();
        part[t] += u; __syncthreads();
    }
    unsigned ex = part[t] - (c0 + c1);
    OT[(size_t)b * G1 + 2 * t]     = ex;
    OT[(size_t)b * G1 + 2 * t + 1] = ex + c0;
    if (t == 1023) bucketTotal[b] = part[1023];
}

// K4: exclusive scan over bucket totals
__global__ __launch_bounds__(1024) void bucket_scan_kernel(const unsigned* __restrict__ bucketTotal,
                                                           unsigned* __restrict__ bucketStart) {
    __shared__ unsigned sc[1024];
    int t = threadIdx.x;
    unsigned v = (t < NBUCKETS) ? bucketTotal[t] : 0u;
    sc[t] = v; __syncthreads();
    for (int off = 1; off < 1024; off <<= 1) {
        unsigned u = (t >= off) ? sc[t - off] : 0u;
        __syncthreads();
        sc[t] += u; __syncthreads();
    }
    if (t < NBUCKETS) bucketStart[t] = sc[t] - v;
    if (t == NBUCKETS - 1) bucketStart[NBUCKETS] = sc[t];
}

// K5: blockOffs[blk][b] = OT[b][blk] + bucketStart[b]  (tile transpose)
__global__ void add_transpose_kernel(const unsigned* __restrict__ OT,
                                     const unsigned* __restrict__ bucketStart,
                                     unsigned* __restrict__ blockOffs) {
    __shared__ unsigned tile[32][33];
    int tx = threadIdx.x, ty = threadIdx.y;
    int blk0 = blockIdx.x * 32, b0 = blockIdx.y * 32;
    #pragma unroll
    for (int j = 0; j < 32; j += 8) {
        int b = b0 + ty + j, blk = blk0 + tx;
        if (b < NBUCKETS && blk < G1)
            tile[ty + j][tx] = OT[(size_t)b * G1 + blk] + bucketStart[b];
    }
    __syncthreads();
    #pragma unroll
    for (int j = 0; j < 32; j += 8) {
        int blk = blk0 + ty + j, b = b0 + tx;
        if (b < NBUCKETS && blk < G1)
            blockOffs[(size_t)blk * NBUCKETS + b] = tile[tx][ty + j];
    }
}

// K6: single-pass local sort + coalesced run-flush (39.5 KB LDS).
// XCD-chunked vblk swizzle: physical block p -> vblk v = (p%8)*(G1/8)+p/8,
// so each XCD owns a contiguous slice of every bucket's run region and
// line-straddling partial writes merge in that XCD's L2.
__global__ __launch_bounds__(512) void scatter2_kernel(
        const int* __restrict__ row,
        const int* __restrict__ col,
        const float* __restrict__ w,
        int nE, int espan,
        const unsigned* __restrict__ L,
        const unsigned* __restrict__ blockOffs,
        uint2* __restrict__ payloadA) {
    __shared__ uint2 stage[ESPAN_MAX];           // 26.6 KB
    __shared__ unsigned short sbkt[ESPAN_MAX];   // 6.7 KB
    __shared__ unsigned cur[NBUCKETS];           // 3.1 KB
    __shared__ unsigned diff[NBUCKETS];          // 3.1 KB
    int t = threadIdx.x;
    int p = blockIdx.x;
    int v = (p & 7) * (G1 / 8) + (p >> 3);       // chunked XCD swizzle (bijective)
    long e0 = (long)v * espan;
    long rem = (long)nE - e0;
    int n = (int)(rem > (long)espan ? espan : (rem < 0 ? 0 : rem));
    size_t lrow = (size_t)v * LSROW;

    for (int i = t; i < NBUCKETS; i += 512) {
        unsigned lv = L[lrow + i];
        cur[i]  = lv;
        diff[i] = blockOffs[(size_t)v * NBUCKETS + i] - lv;
    }
    __syncthreads();

    for (int k = t; k < n; k += 512) {
        unsigned c = (unsigned)col[e0 + k];
        unsigned b = c >> BSHIFT;
        unsigned pos = atomicAdd(&cur[b], 1u);
        stage[pos] = make_uint2(((unsigned)row[e0 + k] << BSHIFT) | (c & (NB - 1)),
                                __float_as_uint(w[e0 + k]));
        sbkt[pos] = (unsigned short)b;
    }
    __syncthreads();

    for (int k = t; k < n; k += 512) {
        unsigned b = sbkt[k];
        payloadA[diff[b] + (unsigned)k] = stage[k];
    }
}

// K7 (fused, 1024 threads): per-bucket in-LDS node sort + register gather.
__global__ __launch_bounds__(1024) void bucket_sort_gather_kernel(
        const float* __restrict__ x,
        const uint2* __restrict__ payloadA,
        const unsigned* __restrict__ bucketStart,
        float* __restrict__ out) {
    __shared__ uint2 stage[CAP];          // 76 KB
    __shared__ unsigned cnt[NB];
    __shared__ unsigned scanb[NB];
    __shared__ unsigned exs[NB + 1];
    int b = blockIdx.x, t = threadIdx.x;
    int e0 = (int)bucketStart[b], e1 = (int)bucketStart[b + 1];
    int n = e1 - e0;

    if (t < NB) cnt[t] = 0;
    __syncthreads();

    if (n <= CAP) {
        for (int k = t; k < n; k += 1024)
            atomicAdd(&cnt[payloadA[e0 + k].x & (NB - 1)], 1u);
        __syncthreads();
        if (t < NB) scanb[t] = cnt[t];
        __syncthreads();
        for (int off = 1; off < NB; off <<= 1) {
            unsigned v = 0;
            if (t < NB && t >= off) v = scanb[t - off];
            __syncthreads();
            if (t < NB) scanb[t] += v;
            __syncthreads();
        }
        if (t < NB) {
            unsigned ex = scanb[t] - cnt[t];
            exs[t] = ex;
            cnt[t] = ex;                  // cursor
        }
        if (t == 0) exs[NB] = (unsigned)n;
        __syncthreads();

        for (int k = t; k < n; k += 1024) {
            uint2 p = payloadA[e0 + k];
            unsigned node = p.x & (NB - 1);
            unsigned pos = atomicAdd(&cnt[node], 1u);
            stage[pos] = make_uint2(p.x >> BSHIFT, p.y);
        }
        __syncthreads();

        // 1024 slots, 1024 threads: one (node,dim) per thread
        int slot = t;
        int node = slot >> 3, d = slot & 7;
        int gn = b * NB + node;
        if (gn < N_NODES) {
            float xc = x[(size_t)gn * DIM + d];
            int e = (int)exs[node], eEnd = (int)exs[node + 1];
            float a0 = 0.f, a1 = 0.f;
            for (; e + 4 <= eEnd; e += 4) {
                uint2 p0 = stage[e];
                uint2 p1 = stage[e + 1];
                uint2 p2 = stage[e + 2];
                uint2 p3 = stage[e + 3];
                float s0 = x[(size_t)p0.x * DIM + d];
                float s1 = x[(size_t)p1.x * DIM + d];
                float s2 = x[(size_t)p2.x * DIM + d];
                float s3 = x[(size_t)p3.x * DIM + d];
                a0 += (s0 - xc) * __uint_as_float(p0.y);
                a1 += (s1 - xc) * __uint_as_float(p1.y);
                a0 += (s2 - xc) * __uint_as_float(p2.y);
                a1 += (s3 - xc) * __uint_as_float(p3.y);
            }
            for (; e < eEnd; ++e) {
                uint2 p = stage[e];
                a0 += (x[(size_t)p.x * DIM + d] - xc) * __uint_as_float(p.y);
            }
            out[(size_t)gn * DIM + d] = a0 + a1 - xc;
        }
    } else {
        // overflow guard (statistically impossible): -x init + global atomics
        for (int slot = t; slot < NB * DIM; slot += 1024) {
            int gn = b * NB + (slot >> 3);
            if (gn < N_NODES) {
                size_t gi = (size_t)b * NB * DIM + slot;
                out[gi] = -x[gi];
            }
        }
        __syncthreads();
        int d = t & 7, sub = t >> 3;
        for (int k = sub; k < n; k += 128) {
            uint2 p = payloadA[e0 + k];
            int node = (int)(p.x & (NB - 1));
            int r = (int)(p.x >> BSHIFT);
            int gn = b * NB + node;
            if (gn < N_NODES) {
                float xc = x[(size_t)gn * DIM + d];
                atomicAdd(&out[(size_t)gn * DIM + d],
                          (x[(size_t)r * DIM + d] - xc) * __uint_as_float(p.y));
            }
        }
    }
}

extern "C" void kernel_launch(void* const* d_in, const int* in_sizes, int n_in,
                              void* d_out, int out_size, void* d_ws, size_t ws_size,
                              hipStream_t stream) {
    const float* x   = (const float*)d_in[0];
    const int*   row = (const int*)d_in[1];
    const int*   col = (const int*)d_in[2];
    const float* w   = (const float*)d_in[3];
    float* out = (float*)d_out;
    int nE = in_sizes[1];
    int n4 = out_size / 4;

    int espan = (nE + G1 - 1) / G1;

    auto align256 = [](size_t v) { return (v + 255) & ~(size_t)255; };
    size_t off_payloadA  = 0;
    size_t off_L         = align256(off_payloadA + (size_t)nE * sizeof(uint2));
    size_t off_LT        = align256(off_L  + (size_t)G1 * LSROW * 4);
    size_t off_OT        = align256(off_LT + (size_t)LSROW * G1 * 4);
    size_t off_blockOffs = align256(off_OT + (size_t)NBUCKETS * G1 * 4);
    size_t off_total     = align256(off_blockOffs + (size_t)G1 * NBUCKETS * 4);
    size_t off_start     = align256(off_total + (size_t)NBUCKETS * 4);
    size_t need          = off_start + (size_t)(NBUCKETS + 1) * 4;

    if (ws_size < need || espan > ESPAN_MAX) {
        init_neg_kernel<<<(n4 + 255) / 256, 256, 0, stream>>>(x, out, n4);
        edge_scatter_atomic<<<(nE + 255) / 256, 256, 0, stream>>>(x, row, col, w, out, nE);
        return;
    }

    char* p = (char*)d_ws;
    uint2*    payloadA    = (uint2*)(p + off_payloadA);
    unsigned* L           = (unsigned*)(p + off_L);
    unsigned* LT          = (unsigned*)(p + off_LT);
    unsigned* OT          = (unsigned*)(p + off_OT);
    unsigned* blockOffs   = (unsigned*)(p + off_blockOffs);
    unsigned* bucketTotal = (unsigned*)(p + off_total);
    unsigned* bucketStart = (unsigned*)(p + off_start);

    hist_scan_kernel<<<G1, 256, 0, stream>>>(col, nE, espan, L);
    transpose_kernel<<<dim3((LSROW + 31) / 32, G1 / 32), dim3(32, 8), 0, stream>>>(
        L, LT, G1, LSROW);
    col_scan_kernel<<<NBUCKETS, 1024, 0, stream>>>(LT, OT, bucketTotal);
    bucket_scan_kernel<<<1, 1024, 0, stream>>>(bucketTotal, bucketStart);
    add_transpose_kernel<<<dim3(G1 / 32, (NBUCKETS + 31) / 32), dim3(32, 8), 0, stream>>>(
        OT, bucketStart, blockOffs);
    scatter2_kernel<<<G1, 512, 0, stream>>>(row, col, w, nE, espan, L,
                                            blockOffs, payloadA);
    bucket_sort_gather_kernel<<<NBUCKETS, 1024, 0, stream>>>(x, payloadA,
                                                             bucketStart, out);
}

// Round 15
// 106.712 us; speedup vs baseline: 1.6895x; 1.0303x over previous
//
#include <hip/hip_runtime.h>

#define N_NODES 100000
#define DIM 8
#define NB 128                 // nodes per bucket
#define BSHIFT 7               // log2(NB)
#define NBUCKETS ((N_NODES + NB - 1) / NB)   // 782
#define LSROW (NBUCKETS + 1)   // 783 (local-scan row incl. sentinel)
#define G1 2048                // partition blocks
#define ESPAN_MAX 3328         // LDS stage cap for scatter
#define CAP 9728               // max edges per bucket (mean 8184, ~17 sigma)
#define NPER 10                // ceil(CAP / 1024) register-staged edges per thread

// ---------------- fallback (atomic path) ----------------
__global__ void init_neg_kernel(const float* __restrict__ x,
                                float* __restrict__ out, int n4) {
    int i = blockIdx.x * blockDim.x + threadIdx.x;
    if (i < n4) {
        float4 v = reinterpret_cast<const float4*>(x)[i];
        float4 o; o.x = -v.x; o.y = -v.y; o.z = -v.z; o.w = -v.w;
        reinterpret_cast<float4*>(out)[i] = o;
    }
}

__global__ void edge_scatter_atomic(const float* __restrict__ x,
                                    const int* __restrict__ row,
                                    const int* __restrict__ col,
                                    const float* __restrict__ w,
                                    float* __restrict__ out, int nE) {
    int e = blockIdx.x * blockDim.x + threadIdx.x;
    if (e >= nE) return;
    int r = row[e], c = col[e];
    float we = w[e];
    const float4* xr = reinterpret_cast<const float4*>(x + (size_t)r * DIM);
    const float4* xc = reinterpret_cast<const float4*>(x + (size_t)c * DIM);
    float4 a0 = xr[0], a1 = xr[1], b0 = xc[0], b1 = xc[1];
    float* o = out + (size_t)c * DIM;
    atomicAdd(o + 0, (a0.x - b0.x) * we); atomicAdd(o + 1, (a0.y - b0.y) * we);
    atomicAdd(o + 2, (a0.z - b0.z) * we); atomicAdd(o + 3, (a0.w - b0.w) * we);
    atomicAdd(o + 4, (a1.x - b1.x) * we); atomicAdd(o + 5, (a1.y - b1.y) * we);
    atomicAdd(o + 6, (a1.z - b1.z) * we); atomicAdd(o + 7, (a1.w - b1.w) * we);
}

// ---------------- R15 pipeline (R14 + register-staged K7) ----------------

// K1: per-block histogram + LOCAL exclusive scan, coalesced L[blk][0..782]
__global__ __launch_bounds__(256) void hist_scan_kernel(const int* __restrict__ col,
                                                        int nE, int espan,
                                                        unsigned* __restrict__ L) {
    __shared__ unsigned cnt[NBUCKETS];
    __shared__ unsigned part[256];
    int t = threadIdx.x, blk = blockIdx.x;
    long e0 = (long)blk * espan;
    long rem = (long)nE - e0;
    int n = (int)(rem > (long)espan ? espan : (rem < 0 ? 0 : rem));

    for (int i = t; i < NBUCKETS; i += 256) cnt[i] = 0;
    __syncthreads();
    for (int k = t; k < n; k += 256)
        atomicAdd(&cnt[((unsigned)col[e0 + k]) >> BSHIFT], 1u);
    __syncthreads();

    unsigned v[4], s = 0;
    #pragma unroll
    for (int j = 0; j < 4; ++j) {
        int b = 4 * t + j;
        v[j] = (b < NBUCKETS) ? cnt[b] : 0u;
        s += v[j];
    }
    part[t] = s; __syncthreads();
    for (int off = 1; off < 256; off <<= 1) {
        unsigned u = (t >= off) ? part[t - off] : 0u;
        __syncthreads();
        part[t] += u; __syncthreads();
    }
    unsigned base = part[t] - s;
    size_t lrow = (size_t)blk * LSROW;
    #pragma unroll
    for (int j = 0; j < 4; ++j) {
        int b = 4 * t + j;
        if (b < NBUCKETS) { L[lrow + b] = base; base += v[j]; }
    }
    if (t == 255) L[lrow + NBUCKETS] = part[255];   // == n
}

// K2: tile transpose  in[R][C] -> out[C][R]
__global__ void transpose_kernel(const unsigned* __restrict__ in,
                                 unsigned* __restrict__ outp, int R, int C) {
    __shared__ unsigned tile[32][33];
    int tx = threadIdx.x, ty = threadIdx.y;
    int c0 = blockIdx.x * 32, r0 = blockIdx.y * 32;
    #pragma unroll
    for (int j = 0; j < 32; j += 8) {
        int r = r0 + ty + j, c = c0 + tx;
        if (r < R && c < C) tile[ty + j][tx] = in[(size_t)r * C + c];
    }
    __syncthreads();
    #pragma unroll
    for (int j = 0; j < 32; j += 8) {
        int c = c0 + ty + j, r = r0 + tx;
        if (r < R && c < C) outp[(size_t)c * R + r] = tile[tx][ty + j];
    }
}

// K3: per-bucket cross-block scan (coalesced rows of LT) -> OT, bucketTotal
__global__ __launch_bounds__(1024) void col_scan_kernel(const unsigned* __restrict__ LT,
                                                        unsigned* __restrict__ OT,
                                                        unsigned* __restrict__ bucketTotal) {
    __shared__ unsigned part[1024];
    int b = blockIdx.x, t = threadIdx.x;
    const unsigned* r0 = LT + (size_t)b * G1;
    const unsigned* r1 = LT + (size_t)(b + 1) * G1;
    unsigned c0 = r1[2 * t] - r0[2 * t];
    unsigned c1 = r1[2 * t + 1] - r0[2 * t + 1];
    part[t] = c0 + c1; __syncthreads();
    for (int off = 1; off < 1024; off <<= 1) {
        unsigned u = (t >= off) ? part[t - off] : 0u;
        __syncthreads();
        part[t] += u; __syncthreads();
    }
    unsigned ex = part[t] - (c0 + c1);
    OT[(size_t)b * G1 + 2 * t]     = ex;
    OT[(size_t)b * G1 + 2 * t + 1] = ex + c0;
    if (t == 1023) bucketTotal[b] = part[1023];
}

// K4: exclusive scan over bucket totals
__global__ __launch_bounds__(1024) void bucket_scan_kernel(const unsigned* __restrict__ bucketTotal,
                                                           unsigned* __restrict__ bucketStart) {
    __shared__ unsigned sc[1024];
    int t = threadIdx.x;
    unsigned v = (t < NBUCKETS) ? bucketTotal[t] : 0u;
    sc[t] = v; __syncthreads();
    for (int off = 1; off < 1024; off <<= 1) {
        unsigned u = (t >= off) ? sc[t - off] : 0u;
        __syncthreads();
        sc[t] += u; __syncthreads();
    }
    if (t < NBUCKETS) bucketStart[t] = sc[t] - v;
    if (t == NBUCKETS - 1) bucketStart[NBUCKETS] = sc[t];
}

// K5: blockOffs[blk][b] = OT[b][blk] + bucketStart[b]  (tile transpose)
__global__ void add_transpose_kernel(const unsigned* __restrict__ OT,
                                     const unsigned* __restrict__ bucketStart,
                                     unsigned* __restrict__ blockOffs) {
    __shared__ unsigned tile[32][33];
    int tx = threadIdx.x, ty = threadIdx.y;
    int blk0 = blockIdx.x * 32, b0 = blockIdx.y * 32;
    #pragma unroll
    for (int j = 0; j < 32; j += 8) {
        int b = b0 + ty + j, blk = blk0 + tx;
        if (b < NBUCKETS && blk < G1)
            tile[ty + j][tx] = OT[(size_t)b * G1 + blk] + bucketStart[b];
    }
    __syncthreads();
    #pragma unroll
    for (int j = 0; j < 32; j += 8) {
        int blk = blk0 + ty + j, b = b0 + tx;
        if (b < NBUCKETS && blk < G1)
            blockOffs[(size_t)blk * NBUCKETS + b] = tile[tx][ty + j];
    }
}

// K6: single-pass local sort + coalesced run-flush (39.5 KB LDS).
// XCD-chunked vblk swizzle keeps each XCD's runs contiguous (write-merge in L2).
__global__ __launch_bounds__(512) void scatter2_kernel(
        const int* __restrict__ row,
        const int* __restrict__ col,
        const float* __restrict__ w,
        int nE, int espan,
        const unsigned* __restrict__ L,
        const unsigned* __restrict__ blockOffs,
        uint2* __restrict__ payloadA) {
    __shared__ uint2 stage[ESPAN_MAX];           // 26.6 KB
    __shared__ unsigned short sbkt[ESPAN_MAX];   // 6.7 KB
    __shared__ unsigned cur[NBUCKETS];           // 3.1 KB
    __shared__ unsigned diff[NBUCKETS];          // 3.1 KB
    int t = threadIdx.x;
    int p = blockIdx.x;
    int v = (p & 7) * (G1 / 8) + (p >> 3);       // chunked XCD swizzle (bijective)
    long e0 = (long)v * espan;
    long rem = (long)nE - e0;
    int n = (int)(rem > (long)espan ? espan : (rem < 0 ? 0 : rem));
    size_t lrow = (size_t)v * LSROW;

    for (int i = t; i < NBUCKETS; i += 512) {
        unsigned lv = L[lrow + i];
        cur[i]  = lv;
        diff[i] = blockOffs[(size_t)v * NBUCKETS + i] - lv;
    }
    __syncthreads();

    for (int k = t; k < n; k += 512) {
        unsigned c = (unsigned)col[e0 + k];
        unsigned b = c >> BSHIFT;
        unsigned pos = atomicAdd(&cur[b], 1u);
        stage[pos] = make_uint2(((unsigned)row[e0 + k] << BSHIFT) | (c & (NB - 1)),
                                __float_as_uint(w[e0 + k]));
        sbkt[pos] = (unsigned short)b;
    }
    __syncthreads();

    for (int k = t; k < n; k += 512) {
        unsigned b = sbkt[k];
        payloadA[diff[b] + (unsigned)k] = stage[k];
    }
}

// K7 (fused, 1024 threads, register-staged): payload read ONCE into regs,
// count, scan, place from regs into LDS stage, register gather -> out.
__global__ __launch_bounds__(1024) void bucket_sort_gather_kernel(
        const float* __restrict__ x,
        const uint2* __restrict__ payloadA,
        const unsigned* __restrict__ bucketStart,
        float* __restrict__ out) {
    __shared__ uint2 stage[CAP];          // 76 KB
    __shared__ unsigned cnt[NB];
    __shared__ unsigned scanb[NB];
    __shared__ unsigned exs[NB + 1];
    int b = blockIdx.x, t = threadIdx.x;
    int e0 = (int)bucketStart[b], e1 = (int)bucketStart[b + 1];
    int n = e1 - e0;

    if (t < NB) cnt[t] = 0;
    __syncthreads();

    if (n <= CAP) {
        // pass 1: coalesced load into registers + count
        uint2 regs[NPER];
        #pragma unroll
        for (int j = 0; j < NPER; ++j) {
            int k = (j << 10) + t;
            if (k < n) {
                uint2 p = payloadA[e0 + k];
                regs[j] = p;
                atomicAdd(&cnt[p.x & (NB - 1)], 1u);
            }
        }
        __syncthreads();
        if (t < NB) scanb[t] = cnt[t];
        __syncthreads();
        for (int off = 1; off < NB; off <<= 1) {
            unsigned v = 0;
            if (t < NB && t >= off) v = scanb[t - off];
            __syncthreads();
            if (t < NB) scanb[t] += v;
            __syncthreads();
        }
        if (t < NB) {
            unsigned ex = scanb[t] - cnt[t];
            exs[t] = ex;
            cnt[t] = ex;                  // cursor
        }
        if (t == 0) exs[NB] = (unsigned)n;
        __syncthreads();

        // pass 2: place from registers (no global re-read)
        #pragma unroll
        for (int j = 0; j < NPER; ++j) {
            int k = (j << 10) + t;
            if (k < n) {
                uint2 p = regs[j];
                unsigned node = p.x & (NB - 1);
                unsigned pos = atomicAdd(&cnt[node], 1u);
                stage[pos] = make_uint2(p.x >> BSHIFT, p.y);
            }
        }
        __syncthreads();

        // 1024 slots, 1024 threads: one (node,dim) per thread
        int slot = t;
        int node = slot >> 3, d = slot & 7;
        int gn = b * NB + node;
        if (gn < N_NODES) {
            float xc = x[(size_t)gn * DIM + d];
            int e = (int)exs[node], eEnd = (int)exs[node + 1];
            float a0 = 0.f, a1 = 0.f;
            for (; e + 4 <= eEnd; e += 4) {
                uint2 p0 = stage[e];
                uint2 p1 = stage[e + 1];
                uint2 p2 = stage[e + 2];
                uint2 p3 = stage[e + 3];
                float s0 = x[(size_t)p0.x * DIM + d];
                float s1 = x[(size_t)p1.x * DIM + d];
                float s2 = x[(size_t)p2.x * DIM + d];
                float s3 = x[(size_t)p3.x * DIM + d];
                a0 += (s0 - xc) * __uint_as_float(p0.y);
                a1 += (s1 - xc) * __uint_as_float(p1.y);
                a0 += (s2 - xc) * __uint_as_float(p2.y);
                a1 += (s3 - xc) * __uint_as_float(p3.y);
            }
            for (; e < eEnd; ++e) {
                uint2 p = stage[e];
                a0 += (x[(size_t)p.x * DIM + d] - xc) * __uint_as_float(p.y);
            }
            out[(size_t)gn * DIM + d] = a0 + a1 - xc;
        }
    } else {
        // overflow guard (statistically impossible): -x init + global atomics
        for (int slot = t; slot < NB * DIM; slot += 1024) {
            int gn = b * NB + (slot >> 3);
            if (gn < N_NODES) {
                size_t gi = (size_t)b * NB * DIM + slot;
                out[gi] = -x[gi];
            }
        }
        __syncthreads();
        int d = t & 7, sub = t >> 3;
        for (int k = sub; k < n; k += 128) {
            uint2 p = payloadA[e0 + k];
            int node = (int)(p.x & (NB - 1));
            int r = (int)(p.x >> BSHIFT);
            int gn = b * NB + node;
            if (gn < N_NODES) {
                float xc = x[(size_t)gn * DIM + d];
                atomicAdd(&out[(size_t)gn * DIM + d],
                          (x[(size_t)r * DIM + d] - xc) * __uint_as_float(p.y));
            }
        }
    }
}

extern "C" void kernel_launch(void* const* d_in, const int* in_sizes, int n_in,
                              void* d_out, int out_size, void* d_ws, size_t ws_size,
                              hipStream_t stream) {
    const float* x   = (const float*)d_in[0];
    const int*   row = (const int*)d_in[1];
    const int*   col = (const int*)d_in[2];
    const float* w   = (const float*)d_in[3];
    float* out = (float*)d_out;
    int nE = in_sizes[1];
    int n4 = out_size / 4;

    int espan = (nE + G1 - 1) / G1;

    auto align256 = [](size_t v) { return (v + 255) & ~(size_t)255; };
    size_t off_payloadA  = 0;
    size_t off_L         = align256(off_payloadA + (size_t)nE * sizeof(uint2));
    size_t off_LT        = align256(off_L  + (size_t)G1 * LSROW * 4);
    size_t off_OT        = align256(off_LT + (size_t)LSROW * G1 * 4);
    size_t off_blockOffs = align256(off_OT + (size_t)NBUCKETS * G1 * 4);
    size_t off_total     = align256(off_blockOffs + (size_t)G1 * NBUCKETS * 4);
    size_t off_start     = align256(off_total + (size_t)NBUCKETS * 4);
    size_t need          = off_start + (size_t)(NBUCKETS + 1) * 4;

    if (ws_size < need || espan > ESPAN_MAX) {
        init_neg_kernel<<<(n4 + 255) / 256, 256, 0, stream>>>(x, out, n4);
        edge_scatter_atomic<<<(nE + 255) / 256, 256, 0, stream>>>(x, row, col, w, out, nE);
        return;
    }

    char* p = (char*)d_ws;
    uint2*    payloadA    = (uint2*)(p + off_payloadA);
    unsigned* L           = (unsigned*)(p + off_L);
    unsigned* LT          = (unsigned*)(p + off_LT);
    unsigned* OT          = (unsigned*)(p + off_OT);
    unsigned* blockOffs   = (unsigned*)(p + off_blockOffs);
    unsigned* bucketTotal = (unsigned*)(p + off_total);
    unsigned* bucketStart = (unsigned*)(p + off_start);

    hist_scan_kernel<<<G1, 256, 0, stream>>>(col, nE, espan, L);
    transpose_kernel<<<dim3((LSROW + 31) / 32, G1 / 32), dim3(32, 8), 0, stream>>>(
        L, LT, G1, LSROW);
    col_scan_kernel<<<NBUCKETS, 1024, 0, stream>>>(LT, OT, bucketTotal);
    bucket_scan_kernel<<<1, 1024, 0, stream>>>(bucketTotal, bucketStart);
    add_transpose_kernel<<<dim3(G1 / 32, (NBUCKETS + 31) / 32), dim3(32, 8), 0, stream>>>(
        OT, bucketStart, blockOffs);
    scatter2_kernel<<<G1, 512, 0, stream>>>(row, col, w, nE, espan, L,
                                            blockOffs, payloadA);
    bucket_sort_gather_kernel<<<NBUCKETS, 1024, 0, stream>>>(x, payloadA,
                                                             bucketStart, out);
}